// Round 11
// baseline (81.623 us; speedup 1.0000x reference)
//
#include <hip/hip_runtime.h>
#include <hip/hip_bf16.h>
#include <math.h>

#define MARGIN_F 6.0f
// phase = pr / (REL_RANGE/PI) = pr * (PI / 0.03125)
#define PHASE_SCALE 100.53096491487338f

// ---------------------------------------------------------------------------
// K1: fused prep. grid = 16 blocks (one per b), 1024 threads (16 waves).
//  - mean-pool qh[b] (64x768) -> q[768] in LDS
//  - linear 768->18 + sigmoid (one wave per relation)
//  - mixture -> phase -> sincos -> head gather -> complex rotate
// Output layout (ws): rotT[ro][b][h] float4, ro = d>>2 (0..63), b = 0..15,
// h = 0 (re) / 1 (im), at float offset 8192. One k-iter's 32 rot loads all
// fall in a single 1KB window -> base + immediate offsets.
// ---------------------------------------------------------------------------
__global__ void k_prep(const float* __restrict__ qh, const float* __restrict__ W,
                       const float* __restrict__ brel,
                       const float* __restrict__ rel,
                       const float* __restrict__ ent, const int* __restrict__ hid,
                       float* __restrict__ rot) {
    __shared__ float q[768];
    __shared__ float sig[18];
    int b = blockIdx.x;
    int t = threadIdx.x;

    if (t < 768) {
        float s = 0.f;
        const float* base = qh + (size_t)b * 64 * 768 + t;
        #pragma unroll 8
        for (int srow = 0; srow < 64; ++srow) s += base[(size_t)srow * 768];
        q[t] = s * (1.0f / 64.0f);
    }
    __syncthreads();

    int wave = t >> 6, lane = t & 63;
    for (int r = wave; r < 18; r += 16) {
        float p = 0.f;
        for (int h = lane; h < 768; h += 64) p += q[h] * W[r * 768 + h];
        for (int off = 32; off; off >>= 1) p += __shfl_xor(p, off, 64);
        if (lane == 0) sig[r] = 1.0f / (1.0f + expf(-(p + brel[r])));
    }
    __syncthreads();

    if (t < 256) {
        int d = t;
        float pr = 0.f;
        #pragma unroll
        for (int r = 0; r < 18; ++r) pr += sig[r] * rel[r * 256 + d];
        float phase = pr * PHASE_SCALE;
        float sn, cs;
        sincosf(phase, &sn, &cs);
        int h0 = hid[b];
        float reh = ent[(size_t)h0 * 512 + d];
        float imh = ent[(size_t)h0 * 512 + 256 + d];
        float rre = reh * cs - imh * sn;
        float rim = reh * sn + imh * cs;
        float* rotT = rot + 8192;
        size_t base2 = ((size_t)(d >> 2) * 32 + (size_t)b * 2) * 4 + (d & 3);
        rotT[base2]     = rre;  // [ro][b][0]
        rotT[base2 + 4] = rim;  // [ro][b][1]
    }
}

// ---------------------------------------------------------------------------
// K2: lane = entity x d-split; all 16 b accumulate IN-LANE (acc[16], static
// indexing). 1-wave blocks, TILE=8 entities. Entity rows staged to LDS in
// 64-dim chunks with XOR swizzle [row][j^row] (conflict-free b128 reads;
// round 9's +pad layout was 692K conflicts). rot read via rotT: 32 vector
// loads per k-iter from one 1KB window, each amortized over 8 entities.
// No per-entity reduce: 3 shuffles per b per 8-entity tile.
// ---------------------------------------------------------------------------
#define TILE 8

__global__ __launch_bounds__(64) void k_dist(const float* __restrict__ ent,
                                             const float* __restrict__ rot,
                                             float* __restrict__ out, int E) {
    __shared__ float4 lre[TILE][16];
    __shared__ float4 lim[TILE][16];

    int lane = threadIdx.x;  // 0..63
    int s = lane >> 3;       // d-split 0..7
    int e = lane & 7;        // entity within tile
    int e0 = blockIdx.x * TILE;
    int ei = e0 + e;

    const float4* rt = (const float4*)(rot + 8192);  // rotT[ro][b][h]

    float acc[16];
    #pragma unroll
    for (int b = 0; b < 16; ++b) acc[b] = 0.f;

    for (int c = 0; c < 4; ++c) {  // 4 chunks of 64 dims
        __syncthreads();
        // stage 8 rows x 16 f4 x {re,im} = 256 f4 slots, 4 per lane
        #pragma unroll
        for (int p = 0; p < 4; ++p) {
            int slot = p * 64 + lane;  // 0..255
            int half = slot >> 7;      // 0 = re, 1 = im
            int rem = slot & 127;
            int row = rem >> 4;  // 0..7
            int j = rem & 15;    // f4 within chunk
            int er = min(e0 + row, E - 1);
            const float4* g =
                (const float4*)(ent + (size_t)er * 512) + half * 64 + c * 16 + j;
            float4 v = *g;
            (half ? lim : lre)[row][j ^ row] = v;
        }
        __syncthreads();

        #pragma unroll
        for (int k = 0; k < 2; ++k) {
            int slot = s * 2 + k;  // 0..15
            float4 te = lre[e][slot ^ e];
            float4 ti = lim[e][slot ^ e];
            const float4* rbase = rt + ((size_t)c * 16 + slot) * 32;
            #pragma unroll
            for (int b = 0; b < 16; ++b) {
                float4 rr = rbase[b * 2];
                float4 ri = rbase[b * 2 + 1];
                float dx0 = rr.x - te.x, dy0 = ri.x - ti.x;
                float dx1 = rr.y - te.y, dy1 = ri.y - ti.y;
                float dx2 = rr.z - te.z, dy2 = ri.z - ti.z;
                float dx3 = rr.w - te.w, dy3 = ri.w - ti.w;
                float s0 = __builtin_amdgcn_sqrtf(dx0 * dx0 + dy0 * dy0);
                float s1 = __builtin_amdgcn_sqrtf(dx1 * dx1 + dy1 * dy1);
                float s2 = __builtin_amdgcn_sqrtf(dx2 * dx2 + dy2 * dy2);
                float s3 = __builtin_amdgcn_sqrtf(dx3 * dx3 + dy3 * dy3);
                acc[b] += (s0 + s1) + (s2 + s3);
            }
        }
    }

    // reduce across the 8 d-splits (lane bits 3..5)
    #pragma unroll
    for (int b = 0; b < 16; ++b) {
        acc[b] += __shfl_xor(acc[b], 8, 64);
        acc[b] += __shfl_xor(acc[b], 16, 64);
        acc[b] += __shfl_xor(acc[b], 32, 64);
    }

    if (s == 0 && ei < E) {
        #pragma unroll
        for (int b = 0; b < 16; ++b)
            out[(size_t)b * E + ei] = MARGIN_F - acc[b];
    }
}

extern "C" void kernel_launch(void* const* d_in, const int* in_sizes, int n_in,
                              void* d_out, int out_size, void* d_ws,
                              size_t ws_size, hipStream_t stream) {
    const float* qh   = (const float*)d_in[0];  // (16,64,768)
    const float* W    = (const float*)d_in[1];  // (18,768)
    const float* brel = (const float*)d_in[2];  // (18,)
    const float* rel  = (const float*)d_in[3];  // (18,256)
    const float* ent  = (const float*)d_in[4];  // (E,512)
    const int*   hid  = (const int*)d_in[5];    // (16,)
    float* out = (float*)d_out;

    int E = in_sizes[4] / 512;

    float* rot = (float*)d_ws;  // rotT at float offset 8192 (32 KB)

    k_prep<<<dim3(16), 1024, 0, stream>>>(qh, W, brel, rel, ent, hid, rot);

    int nblk = (E + TILE - 1) / TILE;  // 5405 one-wave blocks
    k_dist<<<dim3(nblk), 64, 0, stream>>>(ent, rot, out, E);
}

// Round 12
// 59.193 us; speedup vs baseline: 1.3789x; 1.3789x over previous
//
#include <hip/hip_runtime.h>
#include <hip/hip_bf16.h>
#include <math.h>

#define MARGIN_F 6.0f
// phase = pr / (REL_RANGE/PI) = pr * (PI / 0.03125)
#define PHASE_SCALE 100.53096491487338f

// ---------------------------------------------------------------------------
// K1: fused prep. grid = 16 blocks (one per b), 1024 threads (16 waves).
// rot layout in ws: rot_re[16][256] at float offset 0, rot_im at 4096.
// ---------------------------------------------------------------------------
__global__ void k_prep(const float* __restrict__ qh, const float* __restrict__ W,
                       const float* __restrict__ brel,
                       const float* __restrict__ rel,
                       const float* __restrict__ ent, const int* __restrict__ hid,
                       float* __restrict__ rot) {
    __shared__ float q[768];
    __shared__ float sig[18];
    int b = blockIdx.x;
    int t = threadIdx.x;

    if (t < 768) {
        float s = 0.f;
        const float* base = qh + (size_t)b * 64 * 768 + t;
        #pragma unroll 8
        for (int srow = 0; srow < 64; ++srow) s += base[(size_t)srow * 768];
        q[t] = s * (1.0f / 64.0f);
    }
    __syncthreads();

    int wave = t >> 6, lane = t & 63;
    for (int r = wave; r < 18; r += 16) {
        float p = 0.f;
        for (int h = lane; h < 768; h += 64) p += q[h] * W[r * 768 + h];
        for (int off = 32; off; off >>= 1) p += __shfl_xor(p, off, 64);
        if (lane == 0) sig[r] = 1.0f / (1.0f + expf(-(p + brel[r])));
    }
    __syncthreads();

    if (t < 256) {
        int d = t;
        float pr = 0.f;
        #pragma unroll
        for (int r = 0; r < 18; ++r) pr += sig[r] * rel[r * 256 + d];
        float phase = pr * PHASE_SCALE;
        float sn, cs;
        sincosf(phase, &sn, &cs);
        int h0 = hid[b];
        float reh = ent[(size_t)h0 * 512 + d];
        float imh = ent[(size_t)h0 * 512 + 256 + d];
        rot[b * 256 + d]        = reh * cs - imh * sn;  // rot_re
        rot[4096 + b * 256 + d] = reh * sn + imh * cs;  // rot_im
    }
}

// ---------------------------------------------------------------------------
// K2: 4 waves/block, wave w owns b = 4w..4w+3; block covers b=0..15 over a
// contiguous entity chunk. G=4 entities per iteration:
//  - 8 coalesced float4 row loads issue back-to-back (4-deep mem pipeline)
//  - 4 independent compaction reduce chains interleave (DS latency /4)
// All shapes measured r2..r11 execute ~34us of VALU; the differentiator is
// idle. This attacks idle with in-wave ILP. lane l owns dims 4l..4l+3.
// ---------------------------------------------------------------------------
__global__ __launch_bounds__(256, 4) void k_dist(const float* __restrict__ ent,
                                                 const float* __restrict__ rot,
                                                 float* __restrict__ out, int E,
                                                 int chunk) {
    int lane = threadIdx.x & 63;
    int w4 = threadIdx.x >> 6;  // which 4 b's this wave owns

    const float4* rre4 = (const float4*)rot + (size_t)w4 * 4 * 64;
    const float4* rim4 = (const float4*)(rot + 4096) + (size_t)w4 * 4 * 64;
    float4 ra[4], ia[4];
    #pragma unroll
    for (int b = 0; b < 4; ++b) {
        ra[b] = rre4[b * 64 + lane];
        ia[b] = rim4[b * 64 + lane];
    }

    // b owned by lane l (<4) after compaction: b = 2*l0 + l1
    int bout = w4 * 4 + (((lane & 1) << 1) | ((lane >> 1) & 1));

    int e0 = blockIdx.x * chunk;
    int e1 = min(e0 + chunk, E);

    for (int e = e0; e < e1; e += 4) {
        // 8 loads up front: 4-deep per-wave memory pipeline
        float4 te[4], ti[4];
        #pragma unroll
        for (int g = 0; g < 4; ++g) {
            int ee = min(e + g, e1 - 1);  // clamp tail reads (stores guarded)
            const float4* r4 = (const float4*)(ent + (size_t)ee * 512);
            te[g] = r4[lane];
            ti[g] = r4[64 + lane];
        }

        float v[4][4];
        #pragma unroll
        for (int g = 0; g < 4; ++g) {
            #pragma unroll
            for (int b = 0; b < 4; ++b) {
                float dx0 = ra[b].x - te[g].x, dy0 = ia[b].x - ti[g].x;
                float dx1 = ra[b].y - te[g].y, dy1 = ia[b].y - ti[g].y;
                float dx2 = ra[b].z - te[g].z, dy2 = ia[b].z - ti[g].z;
                float dx3 = ra[b].w - te[g].w, dy3 = ia[b].w - ti[g].w;
                float s0 = __builtin_amdgcn_sqrtf(dx0 * dx0 + dy0 * dy0);
                float s1 = __builtin_amdgcn_sqrtf(dx1 * dx1 + dy1 * dy1);
                float s2 = __builtin_amdgcn_sqrtf(dx2 * dx2 + dy2 * dy2);
                float s3 = __builtin_amdgcn_sqrtf(dx3 * dx3 + dy3 * dy3);
                v[g][b] = (s0 + s1) + (s2 + s3);
            }
        }

        // 4 interleaved compaction reduces (4 vals x 64 lanes -> lanes 0..3)
        #pragma unroll
        for (int i = 0; i < 2; ++i) {
            #pragma unroll
            for (int g = 0; g < 4; ++g) {
                float s = (lane & 1) ? v[g][i] : v[g][i + 2];
                float c = __shfl_xor(s, 1, 64);
                v[g][i] = ((lane & 1) ? v[g][i + 2] : v[g][i]) + c;
            }
        }
        #pragma unroll
        for (int g = 0; g < 4; ++g) {
            float s = (lane & 2) ? v[g][0] : v[g][1];
            float c = __shfl_xor(s, 2, 64);
            v[g][0] = ((lane & 2) ? v[g][1] : v[g][0]) + c;
        }
        #pragma unroll
        for (int g = 0; g < 4; ++g) v[g][0] += __shfl_xor(v[g][0], 4, 64);
        #pragma unroll
        for (int g = 0; g < 4; ++g) v[g][0] += __shfl_xor(v[g][0], 8, 64);
        #pragma unroll
        for (int g = 0; g < 4; ++g) v[g][0] += __shfl_xor(v[g][0], 16, 64);
        #pragma unroll
        for (int g = 0; g < 4; ++g) v[g][0] += __shfl_xor(v[g][0], 32, 64);

        if (lane < 4) {
            #pragma unroll
            for (int g = 0; g < 4; ++g)
                if (e + g < e1)
                    out[(size_t)bout * E + e + g] = MARGIN_F - v[g][0];
        }
    }
}

extern "C" void kernel_launch(void* const* d_in, const int* in_sizes, int n_in,
                              void* d_out, int out_size, void* d_ws,
                              size_t ws_size, hipStream_t stream) {
    const float* qh   = (const float*)d_in[0];  // (16,64,768)
    const float* W    = (const float*)d_in[1];  // (18,768)
    const float* brel = (const float*)d_in[2];  // (18,)
    const float* rel  = (const float*)d_in[3];  // (18,256)
    const float* ent  = (const float*)d_in[4];  // (E,512)
    const int*   hid  = (const int*)d_in[5];    // (16,)
    float* out = (float*)d_out;

    int E = in_sizes[4] / 512;

    float* rot = (float*)d_ws;  // 2*16*256 floats = 32 KB

    k_prep<<<dim3(16), 1024, 0, stream>>>(qh, W, brel, rel, ent, hid, rot);

    const int NB = 2048;            // 8192 waves
    int chunk = (E + NB - 1) / NB;  // ~22 consecutive entities per block
    k_dist<<<dim3(NB), 256, 0, stream>>>(ent, rot, out, E, chunk);
}